// Round 1
// 482.520 us; speedup vs baseline: 1.0668x; 1.0668x over previous
//
#include <hip/hip_runtime.h>
#include <hip/hip_bf16.h>
#include <math.h>

#define IN_F   128
#define OUT_F  128
#define HEADS  8
#define HEAD_D 16
#define EDGE_F 64
#define BUCKET 64     // CSR bucket capacity per node

typedef __attribute__((ext_vector_type(8))) short bf16x8;
typedef __attribute__((ext_vector_type(4))) float f32x4;

// round-to-nearest-even fp32 -> bf16 bits
__device__ inline unsigned int f2bf(float f) {
    union { float f; unsigned int u; } c; c.f = f;
    unsigned int r = c.u + 0x7FFFu + ((c.u >> 16) & 1u);
    return r >> 16;
}

// kvp feature -> word permutation: word holds (k,v) packed; lane l ulong-loads
// words {2l, 2l+1} = features {h*16+r, h*16+r+8} with h=l>>3, r=l&7.
// wperm(col) = (col & 0x70) | ((col & 7) << 1) | ((col >> 3) & 1)
__device__ inline int wperm(int col) {
    return (col & 0x70) | ((col & 7) << 1) | ((col >> 3) & 1);
}

// ---- Prep: swizzle Wq/Wk/Wv/Wo into MFMA B-frag layout + zero deg ----
// Wb[((mat*8+ct)*4+kb)*64 + lane] = 8 bf16: W[kb*32+(lane>>4)*8+j][ct*16+(lane&15)]
__global__ __launch_bounds__(256)
void prep_kernel(const float* __restrict__ Wq, const float* __restrict__ Wk,
                 const float* __restrict__ Wv, const float* __restrict__ Wo,
                 uint4* __restrict__ Wb, int* __restrict__ deg, int n_nodes) {
    int id = blockIdx.x * 256 + threadIdx.x;
    if (id < n_nodes) deg[id] = 0;
    if (id >= 8192) return;
    int lane = id & 63;
    int kb   = (id >> 6) & 3;
    int ct   = (id >> 8) & 7;
    int mat  = id >> 11;
    const float* W = (mat == 0) ? Wq : (mat == 1) ? Wk : (mat == 2) ? Wv : Wo;
    int n  = ct * 16 + (lane & 15);
    int k0 = kb * 32 + (lane >> 4) * 8;
    unsigned int t[8];
    #pragma unroll
    for (int j = 0; j < 8; ++j) t[j] = f2bf(W[(size_t)(k0 + j) * 128 + n]);
    uint4 val;
    val.x = t[0] | (t[1] << 16);
    val.y = t[2] | (t[3] << 16);
    val.z = t[4] | (t[5] << 16);
    val.w = t[6] | (t[7] << 16);
    Wb[id] = val;
}

// ---- Fused: QKV (node blocks) + edge-bias + CSR scatter (edge blocks) ----
__global__ __launch_bounds__(256)
void qkv_edges(const float* __restrict__ x, const bf16x8* __restrict__ WbV,
               const float* __restrict__ bq, const float* __restrict__ bk,
               const float* __restrict__ bv,
               float* __restrict__ q, unsigned int* __restrict__ kvp, int n_nodes,
               const float* __restrict__ ef, const float* __restrict__ We,
               const float* __restrict__ be, float* __restrict__ ebias,
               const int* __restrict__ ei, int* __restrict__ deg,
               int2* __restrict__ csr2, int n_edges, int node_blocks) {
    __shared__ float sWe[EDGE_F * HEADS];
    __shared__ float sbe[HEADS];
    const int tid = threadIdx.x;

    if ((int)blockIdx.x < node_blocks) {
        // ----------------- QKV via MFMA: 4 waves, 64 nodes/block -----------------
        const int wave = tid >> 6;
        const int lane = tid & 63;
        const int quad = lane >> 4;
        const int lcol = lane & 15;
        const int row0 = blockIdx.x * 64 + wave * 16;
        const int m    = row0 + lcol;                 // A-row this lane loads

        bf16x8 afrag[4];
        const bool mv = (m < n_nodes);
        const float* xr = x + (size_t)m * IN_F;
        #pragma unroll
        for (int kb = 0; kb < 4; ++kb) {
            float buf[8];
            if (mv) {
                float4 a = ((const float4*)(xr + kb * 32 + quad * 8))[0];
                float4 b = ((const float4*)(xr + kb * 32 + quad * 8 + 4))[0];
                buf[0]=a.x; buf[1]=a.y; buf[2]=a.z; buf[3]=a.w;
                buf[4]=b.x; buf[5]=b.y; buf[6]=b.z; buf[7]=b.w;
            } else {
                #pragma unroll
                for (int j = 0; j < 8; ++j) buf[j] = 0.f;
            }
            bf16x8 f;
            #pragma unroll
            for (int j = 0; j < 8; ++j) f[j] = (short)f2bf(buf[j]);
            afrag[kb] = f;
        }

        #pragma unroll
        for (int ct = 0; ct < 8; ++ct) {
            f32x4 aq = {0.f,0.f,0.f,0.f}, ak = {0.f,0.f,0.f,0.f}, av = {0.f,0.f,0.f,0.f};
            #pragma unroll
            for (int kb = 0; kb < 4; ++kb) {
                bf16x8 bq_ = WbV[((0 * 8 + ct) * 4 + kb) * 64 + lane];
                bf16x8 bk_ = WbV[((1 * 8 + ct) * 4 + kb) * 64 + lane];
                bf16x8 bv_ = WbV[((2 * 8 + ct) * 4 + kb) * 64 + lane];
                aq = __builtin_amdgcn_mfma_f32_16x16x32_bf16(afrag[kb], bq_, aq, 0, 0, 0);
                ak = __builtin_amdgcn_mfma_f32_16x16x32_bf16(afrag[kb], bk_, ak, 0, 0, 0);
                av = __builtin_amdgcn_mfma_f32_16x16x32_bf16(afrag[kb], bv_, av, 0, 0, 0);
            }
            const int col = ct * 16 + lcol;
            const int wcol = wperm(col);
            float bqc = bq[col], bkc = bk[col], bvc = bv[col];
            #pragma unroll
            for (int r = 0; r < 4; ++r) {
                int node = row0 + quad * 4 + r;       // C/D: row = quad*4+reg, col = lane&15
                if (node < n_nodes) {
                    q[(size_t)node * OUT_F + col]    = aq[r] + bqc;
                    kvp[(size_t)node * OUT_F + wcol] = f2bf(ak[r] + bkc) | (f2bf(av[r] + bvc) << 16);
                }
            }
        }
    } else {
        // ----------------- Edge bias + bucketed CSR scatter -----------------
        for (int i = tid; i < EDGE_F * HEADS; i += 256) sWe[i] = We[i];
        if (tid < HEADS) sbe[tid] = be[tid];
        __syncthreads();

        const int e = (blockIdx.x - node_blocks) * 256 + tid;
        if (e >= n_edges) return;

        int s = ei[e];
        int t = ei[n_edges + e];
        int pos = atomicAdd(&deg[t], 1);
        if (pos < BUCKET) csr2[((size_t)t << 6) + pos] = make_int2(s, e);

        float acc[HEADS];
        #pragma unroll
        for (int h = 0; h < HEADS; ++h) acc[h] = sbe[h];

        const float4* er = (const float4*)(ef + (size_t)e * EDGE_F);
        #pragma unroll
        for (int j4 = 0; j4 < EDGE_F / 4; ++j4) {
            float4 evv = er[j4];
            float ev[4] = {evv.x, evv.y, evv.z, evv.w};
            #pragma unroll
            for (int jj = 0; jj < 4; ++jj) {
                int j = j4 * 4 + jj;
                #pragma unroll
                for (int h = 0; h < HEADS; ++h)
                    acc[h] = fmaf(ev[jj], sWe[j * HEADS + h], acc[h]);
            }
        }
        float4* dst = (float4*)(ebias + (size_t)e * HEADS);
        dst[0] = make_float4(acc[0], acc[1], acc[2], acc[3]);
        dst[1] = make_float4(acc[4], acc[5], acc[6], acc[7]);
    }
}

// ---- Aggregation: 1 wave (64 lanes) per target, 4 targets/block, 4-deep pipeline ----
// lane l owns features fa = (l>>3)*16 + (l&7) and fb = fa+8 via one ulong kvp load.
// In-lane pair add replicates the old mask-8 shuffle level -> bit-identical tree.
__global__ __launch_bounds__(256)
void agg_kernel(const int2* __restrict__ csr2, const int* __restrict__ deg,
                const float* __restrict__ q, const unsigned long long* __restrict__ kvpu,
                const float* __restrict__ ebias, unsigned short* __restrict__ aggn,
                int n_nodes) {
    const int tid  = threadIdx.x;
    const int wave = tid >> 6;
    const int lane = tid & 63;
    const int t    = blockIdx.x * 4 + wave;
    if (t >= n_nodes) return;

    const int h  = lane >> 3;
    const int r  = lane & 7;
    const int fa = h * 16 + r;          // fb = fa + 8

    const float qa = q[(size_t)t * OUT_F + fa];
    const float qb = q[(size_t)t * OUT_F + fa + 8];

    const int beg = t << 6;
    int cnt = deg[t]; if (cnt > BUCKET) cnt = BUCKET;
    const int end = beg + cnt;

    float acc_a = 0.f, acc_b = 0.f, den = 0.f;

    auto process = [&](unsigned long long kv, float eb) {
        unsigned int w0 = (unsigned int)kv;
        unsigned int w1 = (unsigned int)(kv >> 32);
        float ka = __uint_as_float(w0 << 16);
        float va = __uint_as_float(w0 & 0xFFFF0000u);
        float kb = __uint_as_float(w1 << 16);
        float vb = __uint_as_float(w1 & 0xFFFF0000u);
        // bit-identical to old: p_f = q*k (mul), then butterfly adds (8,4,2,1)
        float pa = __fmul_rn(qa, ka);
        float pb = __fmul_rn(qb, kb);
        float p  = __fadd_rn(pa, pb);                   // = old mask-8 level
        p = __fadd_rn(p, __shfl_xor(p, 4, 8));
        p = __fadd_rn(p, __shfl_xor(p, 2, 8));
        p = __fadd_rn(p, __shfl_xor(p, 1, 8));
        float w = __expf(fmaf(p, 0.25f, eb));
        den += w;
        acc_a = fmaf(w, va, acc_a);
        acc_b = fmaf(w, vb, acc_b);
    };

    unsigned long long kv0 = 0, kv1 = 0, kv2 = 0, kv3 = 0;
    float eb0 = 0.f, eb1 = 0.f, eb2 = 0.f, eb3 = 0.f;

    #define LOADSLOT(kvs, ebs, idx)                                          \
        if ((idx) < end) {                                                   \
            int2 se = csr2[(idx)];                                           \
            kvs = kvpu[(size_t)se.x * 64 + lane];                            \
            ebs = ebias[(size_t)se.y * HEADS + h];                           \
        }

    LOADSLOT(kv0, eb0, beg)
    LOADSLOT(kv1, eb1, beg + 1)
    LOADSLOT(kv2, eb2, beg + 2)
    LOADSLOT(kv3, eb3, beg + 3)

    int i = beg;
    while (i + 3 < end) {
        unsigned long long n0 = 0, n1 = 0, n2 = 0, n3 = 0;
        float f0 = 0.f, f1 = 0.f, f2 = 0.f, f3 = 0.f;
        LOADSLOT(n0, f0, i + 4)
        LOADSLOT(n1, f1, i + 5)
        LOADSLOT(n2, f2, i + 6)
        LOADSLOT(n3, f3, i + 7)
        process(kv0, eb0);
        process(kv1, eb1);
        process(kv2, eb2);
        process(kv3, eb3);
        kv0 = n0; eb0 = f0;
        kv1 = n1; eb1 = f1;
        kv2 = n2; eb2 = f2;
        kv3 = n3; eb3 = f3;
        i += 4;
    }
    if (i < end)     process(kv0, eb0);
    if (i + 1 < end) process(kv1, eb1);
    if (i + 2 < end) process(kv2, eb2);
    #undef LOADSLOT

    float d = den + 1e-10f;
    aggn[(size_t)t * OUT_F + fa]     = (unsigned short)f2bf(acc_a / d);
    aggn[(size_t)t * OUT_F + fa + 8] = (unsigned short)f2bf(acc_b / d);
}

// ---- Output projection via MFMA: aggn (bf16) @ Wo + bo ----
__global__ __launch_bounds__(256)
void out_mfma(const unsigned short* __restrict__ aggn, const bf16x8* __restrict__ WbV,
              const float* __restrict__ bo, float* __restrict__ out, int n_nodes) {
    const int tid  = threadIdx.x;
    const int wave = tid >> 6;
    const int lane = tid & 63;
    const int quad = lane >> 4;
    const int lcol = lane & 15;
    const int row0 = blockIdx.x * 64 + wave * 16;
    const int m    = row0 + lcol;

    bf16x8 afrag[4];
    const bool mv = (m < n_nodes);
    const bf16x8* ar = (const bf16x8*)(aggn + (size_t)m * OUT_F);
    #pragma unroll
    for (int kb = 0; kb < 4; ++kb) {
        if (mv) afrag[kb] = ar[kb * 4 + quad];
        else {
            bf16x8 z;
            #pragma unroll
            for (int j = 0; j < 8; ++j) z[j] = 0;
            afrag[kb] = z;
        }
    }

    #pragma unroll
    for (int ct = 0; ct < 8; ++ct) {
        f32x4 acc = {0.f, 0.f, 0.f, 0.f};
        #pragma unroll
        for (int kb = 0; kb < 4; ++kb) {
            bf16x8 b = WbV[((3 * 8 + ct) * 4 + kb) * 64 + lane];
            acc = __builtin_amdgcn_mfma_f32_16x16x32_bf16(afrag[kb], b, acc, 0, 0, 0);
        }
        const int col = ct * 16 + lcol;
        float boc = bo[col];
        #pragma unroll
        for (int r = 0; r < 4; ++r) {
            int node = row0 + quad * 4 + r;
            if (node < n_nodes) out[(size_t)node * OUT_F + col] = acc[r] + boc;
        }
    }
}

extern "C" void kernel_launch(void* const* d_in, const int* in_sizes, int n_in,
                              void* d_out, int out_size, void* d_ws, size_t ws_size,
                              hipStream_t stream) {
    const float* x  = (const float*)d_in[0];
    const int*   ei = (const int*)  d_in[1];
    const float* ef = (const float*)d_in[2];
    const float* Wq = (const float*)d_in[3];
    const float* bq = (const float*)d_in[4];
    const float* Wk = (const float*)d_in[5];
    const float* bk = (const float*)d_in[6];
    const float* Wv = (const float*)d_in[7];
    const float* bv = (const float*)d_in[8];
    const float* We = (const float*)d_in[9];
    const float* be = (const float*)d_in[10];
    const float* Wo = (const float*)d_in[11];
    const float* bo = (const float*)d_in[12];
    float* out = (float*)d_out;

    const int n_nodes = in_sizes[0] / IN_F;
    const int n_edges = in_sizes[1] / 2;

    char* w = (char*)d_ws;
    float*          q     = (float*)w;          w += (size_t)n_nodes * OUT_F * 4;
    unsigned int*   kvp   = (unsigned int*)w;   w += (size_t)n_nodes * OUT_F * 4;
    float*          ebias = (float*)w;          w += (size_t)n_edges * HEADS * 4;
    unsigned short* aggn  = (unsigned short*)w; w += (size_t)n_nodes * OUT_F * 2;
    uint4*          Wb    = (uint4*)w;          w += (size_t)8192 * 16;
    int*            deg   = (int*)w;            w += (size_t)n_nodes * 4;
    int2*           csr2  = (int2*)w;           // [N*64] (src, edge)

    // 1. weight swizzle + deg zeroing (replaces hipMemsetAsync)
    {
        int threads_needed = (n_nodes > 8192) ? n_nodes : 8192;
        prep_kernel<<<(threads_needed + 255) / 256, 256, 0, stream>>>(
            Wq, Wk, Wv, Wo, Wb, deg, n_nodes);
    }

    // 2. fused QKV + edge-bias + CSR scatter
    {
        int node_blocks = (n_nodes + 63) / 64;
        int edge_blocks = (n_edges + 255) / 256;
        qkv_edges<<<node_blocks + edge_blocks, 256, 0, stream>>>(
            x, (const bf16x8*)Wb, bq, bk, bv, q, kvp, n_nodes,
            ef, We, be, ebias, ei, deg, csr2, n_edges, node_blocks);
    }

    // 3. aggregation (1 wave per target, 4 targets per block)
    agg_kernel<<<(n_nodes + 3) / 4, 256, 0, stream>>>(
        csr2, deg, q, (const unsigned long long*)kvp, ebias, aggn, n_nodes);

    // 4. output projection
    out_mfma<<<(n_nodes + 63) / 64, 256, 0, stream>>>(
        aggn, (const bf16x8*)Wb, bo, out, n_nodes);
}